// Round 2
// baseline (338.353 us; speedup 1.0000x reference)
//
#include <hip/hip_runtime.h>

// FocalCTCLoss on MI355X — round 7 (= round 6 resubmit; container infra flake).
// B=256, T=1024, V=128 (BLANK=127), L=64, S=129.
//
// Round-5 post-mortem: top-5 rocprof dispatches are all 512 MiB harness
// poison fills (~78 us each); fused_kernel is < 77 us, so dur_us ~= 156 us
// of fills + ~45 us of kernel. Our 45 us vs the 21 us HBM floor is the
// consumer wave: serial 6-way-conflicted LDS gather per step, __all check
// every 4 steps, and __syncthreads vmcnt(0) drain killing cross-phase load
// pipelining.
//
// Round-6 bench: "MI355X container failed twice" — infra-level failure, no
// compile error / no fail verdict / no profile. Kernel re-audited (barrier
// uniformity: 18 raw s_barriers on every wave; bounds: global f4 max
// 32767 < 32768, tile4 4095<4096, garr 8191<8192, lblk 255<256; LDS 97.4 KB
// < 160 KB). Resubmitting unchanged.
//
// Design: 3-stage pipeline at CH=64 (18 phases):
//   waves 3..15: T14 async split — issue chunk p+1 global loads to regs,
//                ds_write chunk p + row-sum logs + blank(+eps).
//   waves 1..2 : gather g[t][lane] = tile[t][lab]+eps into a compact
//                conflict-free array — the bank conflicts move OFF the
//                serial critical path.
//   wave 0     : recursion from compact array only (2-way-free ds_read +
//                uniform broadcast), setprio(1), rescale check every 16
//                steps at 2^-75 (tail-safe: 16-step worst-case shrink
//                ~2^-46 keeps values above denormal flush).
// Barriers: s_waitcnt lgkmcnt(0) + raw s_barrier (no vmcnt drain) so HBM
// latency pipelines across phases (verified 8-phase-template sync pattern).

#define EPSF 1e-7f

constexpr int Bb  = 256;
constexpr int Tt  = 1024;
constexpr int Vv  = 128;
constexpr int Ll  = 64;
constexpr int CH  = 64;          // timesteps per chunk
constexpr int NCH = Tt / CH;     // 16 chunks
constexpr int NPH = NCH + 2;     // 18 pipeline phases
constexpr int NLW = 13;          // loader waves (wv 3..15) -> 26 half-waves
constexpr int RPW = 3;           // row-iters per half-wave (26*3 = 78 >= 64)

// ---- DPP helpers -----------------------------------------------------------
template <int Ctrl, int RowMask, int BankMask, bool BoundCtrl>
__device__ __forceinline__ float dppf(float x) {
    return __int_as_float(__builtin_amdgcn_update_dpp(
        0, __float_as_int(x), Ctrl, RowMask, BankMask, BoundCtrl));
}

// Wave-64 sum, valid on lane 63 (inputs >= 0; 0-fill is identity).
__device__ __forceinline__ float wave_sum63(float x) {
    x += dppf<0x111, 0xf, 0xf, true>(x);
    x += dppf<0x112, 0xf, 0xf, true>(x);
    x += dppf<0x114, 0xf, 0xf, true>(x);
    x += dppf<0x118, 0xf, 0xf, true>(x);
    x += dppf<0x142, 0xa, 0xf, false>(x);  // row_bcast15 -> rows 1,3
    x += dppf<0x143, 0xc, 0xf, false>(x);  // row_bcast31 -> rows 2,3
    return x;
}

// Half-wave sums: lane 31 = sum(lanes 0..31), lane 63 = sum(lanes 32..63).
__device__ __forceinline__ float half_sum(float x) {
    x += dppf<0x111, 0xf, 0xf, true>(x);
    x += dppf<0x112, 0xf, 0xf, true>(x);
    x += dppf<0x114, 0xf, 0xf, true>(x);
    x += dppf<0x118, 0xf, 0xf, true>(x);
    x += dppf<0x142, 0xa, 0xf, false>(x);
    return x;
}

// Wave-64 max (non-negative inputs), valid on lane 63.
__device__ __forceinline__ float wave_max63(float x) {
    x = fmaxf(x, dppf<0x111, 0xf, 0xf, true>(x));
    x = fmaxf(x, dppf<0x112, 0xf, 0xf, true>(x));
    x = fmaxf(x, dppf<0x114, 0xf, 0xf, true>(x));
    x = fmaxf(x, dppf<0x118, 0xf, 0xf, true>(x));
    x = fmaxf(x, dppf<0x142, 0xa, 0xf, false>(x));
    x = fmaxf(x, dppf<0x143, 0xc, 0xf, false>(x));
    return x;
}

__device__ __forceinline__ float bcast63(float x) {
    return __int_as_float(__builtin_amdgcn_readlane(__float_as_int(x), 63));
}

// LDS-only barrier: order ds ops, do NOT drain vmcnt (keeps the loaders'
// next-chunk global loads in flight across the phase boundary).
__device__ __forceinline__ void pipe_barrier() {
    asm volatile("s_waitcnt lgkmcnt(0)" ::: "memory");
    __builtin_amdgcn_s_barrier();
    asm volatile("" ::: "memory");
}

// ---- fused 3-stage pipeline: one block per batch element -------------------
__launch_bounds__(1024, 1)
__global__ void fused_kernel(const int* __restrict__ y_true,
                             const float* __restrict__ y_pred,
                             float* __restrict__ focal_ws) {
    const int b    = blockIdx.x;
    const int lane = threadIdx.x & 63;
    const int wv   = threadIdx.x >> 6;  // 0..15

    const float4* yb4 = (const float4*)(y_pred + (size_t)b * Tt * Vv);

    __shared__ float4 tile4[2 * CH * (Vv / 4)];  // 64 KB: raw chunk rows
    __shared__ float  garr[2 * CH * 64];         // 32 KB: gathered qe per t
    __shared__ float  lblk[4 * CH];              //  1 KB: blank+eps per t
    __shared__ float  part[2 * NLW];             // denom log partials
    const float* lrows = (const float*)tile4;

    // ---- DP state (wave 0; meaningful on lane 63) --------------------------
    float a_even = 0.0f, a_odd = 0.0f, a128 = 0.0f, maskf = 0.0f;
    int   eacc = 0, lab = 0;

    if (wv <= 2) {
        lab = y_true[b * Ll + lane];           // label of odd state 2*lane+1
        if (wv == 0) {
            const int labp = __shfl_up(lab, 1);
            maskf  = (lane == 0 || lab != labp) ? 1.0f : 0.0f;
            a_even = (lane == 0) ? 1.0f : 0.0f;  // pre-t0 init
        }
    }

    // ---- loader identity ---------------------------------------------------
    const int w    = wv - 3;
    const int half = lane >> 5;
    const int hw   = 2 * w + half;   // half-wave id 0..25
    const int c32  = lane & 31;
    float ll = 0.0f;                 // lanes 31/63: sum of log2 row-sums

    float4 va[RPW], vb[RPW];

    // prologue: chunk 0 into va
    if (wv >= 3) {
#pragma unroll
        for (int k = 0; k < RPW; ++k) {
            const int r = hw + 2 * NLW * k;
            if (r < CH) va[k] = yb4[r * 32 + c32];
        }
    }

    auto do_step = [&](float qe, float qb, bool chk) {
        const float am1  = dppf<0x138, 0xf, 0xf, true>(a_odd);  // alpha[2i-1]
        const float ne   = (a_even + am1) * qb;
        const float no   = fmaf(maskf, am1, a_odd + a_even) * qe;
        const float n128 = (a128 + a_odd) * qb;  // lane 63 only
        a_even = ne; a_odd = no; a128 = n128;
        if (chk) {  // every 16 steps; values only shrink toward underflow
            const float m = fmaxf(fmaxf(a_even, a_odd), a128);
            if (__all(m < 0x1p-75f)) {
                const float    wmax  = bcast63(wave_max63(m));   // > 0
                const unsigned e     = __float_as_uint(wmax) >> 23;
                const float    scale = __uint_as_float((254u - e) << 23);
                eacc += (int)e - 127;
                a_even *= scale; a_odd *= scale; a128 *= scale;
            }
        }
    };

    auto loader_phase = [&](int p, float4* cur, float4* nxt) {
        if (p + 1 < NCH) {  // issue next chunk's loads first (stay in flight)
            const int gbase = (p + 1) * CH * (Vv / 4);
#pragma unroll
            for (int k = 0; k < RPW; ++k) {
                const int r = hw + 2 * NLW * k;
                if (r < CH) nxt[k] = yb4[gbase + r * 32 + c32];
            }
        }
        if (p < NCH) {      // write current chunk + denominators
            const int lb4 = (p & 1) * CH * (Vv / 4);
#pragma unroll
            for (int k = 0; k < RPW; ++k) {
                const int r = hw + 2 * NLW * k;
                if (r < CH) {
                    tile4[lb4 + r * 32 + c32] = cur[k];
                    const float s =
                        half_sum(cur[k].x + cur[k].y + cur[k].z + cur[k].w);
                    if (c32 == 31) {
                        // lane31: row of half 0, lane63: row of half 1;
                        // their v.w is u[r][127] = blank.
                        lblk[(p & 3) * CH + r] = cur[k].w + EPSF;
                        ll += __log2f(s + (float)Vv * EPSF);
                    }
                }
            }
        } else if (p == NCH) {
            if (c32 == 31) part[hw] = ll;
        }
    };

    auto gather_phase = [&](int p) {
        const int c = p - 1;
        if (c < 0 || c >= NCH) return;
        const int sb = (c & 1) * CH * Vv;
        const int db = (c & 1) * CH * 64;
        const int t0 = (wv - 1) * 32;  // wv1: t 0..31, wv2: t 32..63
#pragma unroll 8
        for (int t = t0; t < t0 + 32; ++t)
            garr[db + t * 64 + lane] = lrows[sb + t * 128 + lab] + EPSF;
    };

    auto consumer_phase = [&](int p) {
        const int c = p - 2;
        if (c < 0) return;
        __builtin_amdgcn_s_setprio(1);
        const float* g  = garr + (c & 1) * CH * 64;
        const float* bl = lblk + (c & 3) * CH;
        constexpr int PD = 8;
        float gq[PD], bq[PD];
#pragma unroll
        for (int d = 0; d < PD; ++d) { gq[d] = g[d * 64 + lane]; bq[d] = bl[d]; }
        for (int t0 = 0; t0 < CH - PD; t0 += PD) {
            const bool c8 = (t0 & 8) != 0;  // checks land at t = 15,31,47 (mod 64)
#pragma unroll
            for (int j = 0; j < PD; ++j) {
                const float qe = gq[j], qb = bq[j];
                const int   tn = t0 + j + PD;
                gq[j] = g[tn * 64 + lane];
                bq[j] = bl[tn];
                do_step(qe, qb, c8 && (j == 7));
            }
        }
#pragma unroll
        for (int j = 0; j < PD; ++j) do_step(gq[j], bq[j], j == 7);  // t=63 check
        __builtin_amdgcn_s_setprio(0);
    };

    // ---- 18 phases, 2 per iteration so the loader reg sets alternate -------
    for (int p = 0; p < NPH; p += 2) {
        if (wv >= 3)      loader_phase(p, va, vb);
        else if (wv >= 1) gather_phase(p);
        else              consumer_phase(p);
        pipe_barrier();
        if (wv >= 3)      loader_phase(p + 1, vb, va);
        else if (wv >= 1) gather_phase(p + 1);
        else              consumer_phase(p + 1);
        pipe_barrier();
    }

    if (wv == 0) {
        float vs = (lane < 2 * NLW) ? part[lane] : 0.0f;
        vs = wave_sum63(vs);
        if (lane == 63) {
            const float acc_ld  = vs;  // sum_t log2(S_t + V*eps)
            const float tot     = fmaxf(a128 + a_odd, 1e-37f);
            const float log2lik = __log2f(tot) + (float)eacc - acc_ld;
            const float ln_lik  = 0.69314718055994530942f * log2lik;
            const float loss    = -ln_lik;
            const float pp      = __expf(ln_lik);
            const float om      = 1.0f - pp;
            focal_ws[b] = 0.25f * om * om * loss;
        }
    }
}

// ---- focal mean -------------------------------------------------------------
__global__ void finalize_kernel(const float* __restrict__ focal_ws,
                                float* __restrict__ out) {
    const int i    = threadIdx.x;  // 256 threads = 4 waves
    const int lane = i & 63;
    const int wv   = i >> 6;

    float f = focal_ws[i];
#pragma unroll
    for (int off = 32; off > 0; off >>= 1) f += __shfl_xor(f, off);

    __shared__ float red[4];
    if (lane == 0) red[wv] = f;
    __syncthreads();
    if (i == 0)
        out[0] = (red[0] + red[1] + red[2] + red[3]) * (1.0f / (float)Bb);
}

extern "C" void kernel_launch(void* const* d_in, const int* in_sizes, int n_in,
                              void* d_out, int out_size, void* d_ws, size_t ws_size,
                              hipStream_t stream) {
    const int*   y_true = (const int*)d_in[0];    // [B, L] int32
    const float* y_pred = (const float*)d_in[1];  // [B, T, V] float32
    float* focal_ws = (float*)d_ws;               // [B]

    fused_kernel<<<Bb, 1024, 0, stream>>>(y_true, y_pred, focal_ws);
    finalize_kernel<<<1, 256, 0, stream>>>(focal_ws, (float*)d_out);
}

// Round 3
// 337.526 us; speedup vs baseline: 1.0024x; 1.0024x over previous
//
#include <hip/hip_runtime.h>

// FocalCTCLoss on MI355X — round 8: 3-stage pipeline, scratch-array fix.
// B=256, T=1024, V=128 (BLANK=127), L=64, S=129.
//
// Round-7 post-mortem: fused_kernel regressed 45 -> 198 us. Counters:
// WRITE_SIZE 16.4 MiB/dispatch (= 64 B/thread scratch; we store only 1 KB),
// VGPR_Count 52 (too low), VALUBusy 4.8%, HBM 5%. The float4 va[3]/vb[3]
// staging arrays were passed to the loader lambda as float4* -> address
// taken -> allocated in scratch (rule #20). Every phase round-tripped the
// staged chunk through HBM-backed scratch; the barrier spread that latency
// to all 16 waves. The pipeline itself was never actually exercised.
//
// Fix (this round, ONLY this): no address-taken arrays anywhere.
//  - loader staging: six named float4 scalars (va0..va2 / vb0..vb2), macro
//    LOADER_PHASE expanded twice per iteration with explicit even/odd sets.
//  - consumer prefetch: 16 named floats, macro-expanded steps.
// Everything else (CH=64, 18 phases, lgkmcnt-only barriers, gather waves,
// rescale every 16 steps at 2^-75) unchanged for a clean A/B vs round 7.

#define EPSF 1e-7f

constexpr int Bb  = 256;
constexpr int Tt  = 1024;
constexpr int Vv  = 128;
constexpr int Ll  = 64;
constexpr int CH  = 64;          // timesteps per chunk
constexpr int NCH = Tt / CH;     // 16 chunks
constexpr int NPH = NCH + 2;     // 18 pipeline phases
constexpr int NLW = 13;          // loader waves (wv 3..15) -> 26 half-waves

// ---- DPP helpers -----------------------------------------------------------
template <int Ctrl, int RowMask, int BankMask, bool BoundCtrl>
__device__ __forceinline__ float dppf(float x) {
    return __int_as_float(__builtin_amdgcn_update_dpp(
        0, __float_as_int(x), Ctrl, RowMask, BankMask, BoundCtrl));
}

// Wave-64 sum, valid on lane 63 (inputs >= 0; 0-fill is identity).
__device__ __forceinline__ float wave_sum63(float x) {
    x += dppf<0x111, 0xf, 0xf, true>(x);
    x += dppf<0x112, 0xf, 0xf, true>(x);
    x += dppf<0x114, 0xf, 0xf, true>(x);
    x += dppf<0x118, 0xf, 0xf, true>(x);
    x += dppf<0x142, 0xa, 0xf, false>(x);  // row_bcast15 -> rows 1,3
    x += dppf<0x143, 0xc, 0xf, false>(x);  // row_bcast31 -> rows 2,3
    return x;
}

// Half-wave sums: lane 31 = sum(lanes 0..31), lane 63 = sum(lanes 32..63).
__device__ __forceinline__ float half_sum(float x) {
    x += dppf<0x111, 0xf, 0xf, true>(x);
    x += dppf<0x112, 0xf, 0xf, true>(x);
    x += dppf<0x114, 0xf, 0xf, true>(x);
    x += dppf<0x118, 0xf, 0xf, true>(x);
    x += dppf<0x142, 0xa, 0xf, false>(x);
    return x;
}

// Wave-64 max (non-negative inputs), valid on lane 63.
__device__ __forceinline__ float wave_max63(float x) {
    x = fmaxf(x, dppf<0x111, 0xf, 0xf, true>(x));
    x = fmaxf(x, dppf<0x112, 0xf, 0xf, true>(x));
    x = fmaxf(x, dppf<0x114, 0xf, 0xf, true>(x));
    x = fmaxf(x, dppf<0x118, 0xf, 0xf, true>(x));
    x = fmaxf(x, dppf<0x142, 0xa, 0xf, false>(x));
    x = fmaxf(x, dppf<0x143, 0xc, 0xf, false>(x));
    return x;
}

__device__ __forceinline__ float bcast63(float x) {
    return __int_as_float(__builtin_amdgcn_readlane(__float_as_int(x), 63));
}

// LDS-only barrier: order ds ops, do NOT drain vmcnt (keeps the loaders'
// next-chunk global loads in flight across the phase boundary).
__device__ __forceinline__ void pipe_barrier() {
    asm volatile("s_waitcnt lgkmcnt(0)" ::: "memory");
    __builtin_amdgcn_s_barrier();
    asm volatile("" ::: "memory");
}

// ---- fused 3-stage pipeline: one block per batch element -------------------
__launch_bounds__(1024, 1)
__global__ void fused_kernel(const int* __restrict__ y_true,
                             const float* __restrict__ y_pred,
                             float* __restrict__ focal_ws) {
    const int b    = blockIdx.x;
    const int lane = threadIdx.x & 63;
    const int wv   = threadIdx.x >> 6;  // 0..15

    const float4* yb4 = (const float4*)(y_pred + (size_t)b * Tt * Vv);

    __shared__ float4 tile4[2 * CH * (Vv / 4)];  // 64 KB: raw chunk rows
    __shared__ float  garr[2 * CH * 64];         // 32 KB: gathered qe per t
    __shared__ float  lblk[4 * CH];              //  1 KB: blank+eps per t
    __shared__ float  part[2 * NLW];             // denom log partials
    const float* lrows = (const float*)tile4;

    // ---- DP state (wave 0; meaningful on lane 63) --------------------------
    float a_even = 0.0f, a_odd = 0.0f, a128 = 0.0f, maskf = 0.0f;
    int   eacc = 0, lab = 0;

    if (wv <= 2) {
        lab = y_true[b * Ll + lane];           // label of odd state 2*lane+1
        if (wv == 0) {
            const int labp = __shfl_up(lab, 1);
            maskf  = (lane == 0 || lab != labp) ? 1.0f : 0.0f;
            a_even = (lane == 0) ? 1.0f : 0.0f;  // pre-t0 init
        }
    }

    // ---- loader identity ---------------------------------------------------
    const int  half = lane >> 5;
    const int  hw   = 2 * (wv - 3) + half;  // half-wave id 0..25 (wv>=3)
    const int  c32  = lane & 31;
    const int  r0   = hw;                   // 0..25  (< CH always)
    const int  r1   = hw + 2 * NLW;         // 26..51 (< CH always)
    const int  r2   = hw + 4 * NLW;         // 52..77 (guarded)
    const bool r2ok = r2 < CH;              // wave-uniform (both halves agree)
    float ll = 0.0f;                        // lanes 31/63: sum log2 row-sums

    // Named staging registers — never address-taken.
    float4 va0, va1, va2, vb0, vb1, vb2;

    // prologue: chunk 0 into va*
    if (wv >= 3) {
        va0 = yb4[r0 * 32 + c32];
        va1 = yb4[r1 * 32 + c32];
        if (r2ok) va2 = yb4[r2 * 32 + c32];
    }

    auto do_step = [&](float qe, float qb, bool chk) {
        const float am1  = dppf<0x138, 0xf, 0xf, true>(a_odd);  // alpha[2i-1]
        const float ne   = (a_even + am1) * qb;
        const float no   = fmaf(maskf, am1, a_odd + a_even) * qe;
        const float n128 = (a128 + a_odd) * qb;  // lane 63 only
        a_even = ne; a_odd = no; a128 = n128;
        if (chk) {  // every 16 steps; values only shrink toward underflow
            const float m = fmaxf(fmaxf(a_even, a_odd), a128);
            if (__all(m < 0x1p-75f)) {
                const float    wmax  = bcast63(wave_max63(m));   // > 0
                const unsigned e     = __float_as_uint(wmax) >> 23;
                const float    scale = __uint_as_float((254u - e) << 23);
                eacc += (int)e - 127;
                a_even *= scale; a_odd *= scale; a128 *= scale;
            }
        }
    };

// Loader phase P: issue chunk P+1 into N*, ds_write chunk P from C*,
// fold row-sum logs; publish denom partials at P == NCH.
#define LOADER_PHASE(P, C0, C1, C2, N0, N1, N2)                              \
    do {                                                                     \
        if ((P) + 1 < NCH) {                                                 \
            const int gb = ((P) + 1) * CH * (Vv / 4);                        \
            N0 = yb4[gb + r0 * 32 + c32];                                    \
            N1 = yb4[gb + r1 * 32 + c32];                                    \
            if (r2ok) N2 = yb4[gb + r2 * 32 + c32];                          \
        }                                                                    \
        if ((P) < NCH) {                                                     \
            const int lb = ((P) & 1) * CH * (Vv / 4);                        \
            const int bb = ((P) & 3) * CH;                                   \
            tile4[lb + r0 * 32 + c32] = C0;                                  \
            tile4[lb + r1 * 32 + c32] = C1;                                  \
            const float s0 = half_sum(C0.x + C0.y + C0.z + C0.w);            \
            const float s1 = half_sum(C1.x + C1.y + C1.z + C1.w);            \
            if (c32 == 31) {                                                 \
                lblk[bb + r0] = C0.w + EPSF;                                 \
                lblk[bb + r1] = C1.w + EPSF;                                 \
                ll += __log2f(s0 + (float)Vv * EPSF) +                       \
                      __log2f(s1 + (float)Vv * EPSF);                        \
            }                                                                \
            if (r2ok) {                                                      \
                tile4[lb + r2 * 32 + c32] = C2;                              \
                const float s2 = half_sum(C2.x + C2.y + C2.z + C2.w);        \
                if (c32 == 31) {                                             \
                    lblk[bb + r2] = C2.w + EPSF;                             \
                    ll += __log2f(s2 + (float)Vv * EPSF);                    \
                }                                                            \
            }                                                                \
        } else if ((P) == NCH) {                                             \
            if (c32 == 31) part[hw] = ll;                                    \
        }                                                                    \
    } while (0)

    auto gather_phase = [&](int p) {
        const int c = p - 1;
        if (c < 0 || c >= NCH) return;
        const int sb = (c & 1) * CH * Vv;
        const int db = (c & 1) * CH * 64;
        const int t0 = (wv - 1) * 32;  // wv1: t 0..31, wv2: t 32..63
#pragma unroll 8
        for (int t = t0; t < t0 + 32; ++t)
            garr[db + t * 64 + lane] = lrows[sb + t * 128 + lab] + EPSF;
    };

    auto consumer_phase = [&](int p) {
        const int c = p - 2;
        if (c < 0) return;
        __builtin_amdgcn_s_setprio(1);
        const float* g  = garr + (c & 1) * CH * 64;
        const float* bl = lblk + (c & 3) * CH;
        // 8-deep prefetch in NAMED registers (no arrays -> no scratch).
        float gq0 = g[0 * 64 + lane], gq1 = g[1 * 64 + lane];
        float gq2 = g[2 * 64 + lane], gq3 = g[3 * 64 + lane];
        float gq4 = g[4 * 64 + lane], gq5 = g[5 * 64 + lane];
        float gq6 = g[6 * 64 + lane], gq7 = g[7 * 64 + lane];
        float bq0 = bl[0], bq1 = bl[1], bq2 = bl[2], bq3 = bl[3];
        float bq4 = bl[4], bq5 = bl[5], bq6 = bl[6], bq7 = bl[7];
#define CSTEP(J, GQ, BQ, CHK)                                                \
        do {                                                                 \
            const float qe = GQ, qb = BQ;                                    \
            const int   tn = t0 + (J) + 8;                                   \
            GQ = g[tn * 64 + lane];                                          \
            BQ = bl[tn];                                                     \
            do_step(qe, qb, CHK);                                            \
        } while (0)
        for (int t0 = 0; t0 < CH - 8; t0 += 8) {
            const bool c8 = (t0 & 8) != 0;  // checks at t = 15,31,47 (mod 64)
            CSTEP(0, gq0, bq0, false);
            CSTEP(1, gq1, bq1, false);
            CSTEP(2, gq2, bq2, false);
            CSTEP(3, gq3, bq3, false);
            CSTEP(4, gq4, bq4, false);
            CSTEP(5, gq5, bq5, false);
            CSTEP(6, gq6, bq6, false);
            CSTEP(7, gq7, bq7, c8);
        }
#undef CSTEP
        // tail t = 56..63 (no reload); check at t = 63.
        do_step(gq0, bq0, false);
        do_step(gq1, bq1, false);
        do_step(gq2, bq2, false);
        do_step(gq3, bq3, false);
        do_step(gq4, bq4, false);
        do_step(gq5, bq5, false);
        do_step(gq6, bq6, false);
        do_step(gq7, bq7, true);
        __builtin_amdgcn_s_setprio(0);
    };

    // ---- 18 phases, 2 per iteration so the staging reg sets alternate ------
    for (int p = 0; p < NPH; p += 2) {
        if (wv >= 3)      LOADER_PHASE(p, va0, va1, va2, vb0, vb1, vb2);
        else if (wv >= 1) gather_phase(p);
        else              consumer_phase(p);
        pipe_barrier();
        if (wv >= 3)      LOADER_PHASE(p + 1, vb0, vb1, vb2, va0, va1, va2);
        else if (wv >= 1) gather_phase(p + 1);
        else              consumer_phase(p + 1);
        pipe_barrier();
    }
#undef LOADER_PHASE

    if (wv == 0) {
        float vs = (lane < 2 * NLW) ? part[lane] : 0.0f;
        vs = wave_sum63(vs);
        if (lane == 63) {
            const float acc_ld  = vs;  // sum_t log2(S_t + V*eps)
            const float tot     = fmaxf(a128 + a_odd, 1e-37f);
            const float log2lik = __log2f(tot) + (float)eacc - acc_ld;
            const float ln_lik  = 0.69314718055994530942f * log2lik;
            const float loss    = -ln_lik;
            const float pp      = __expf(ln_lik);
            const float om      = 1.0f - pp;
            focal_ws[b] = 0.25f * om * om * loss;
        }
    }
}

// ---- focal mean -------------------------------------------------------------
__global__ void finalize_kernel(const float* __restrict__ focal_ws,
                                float* __restrict__ out) {
    const int i    = threadIdx.x;  // 256 threads = 4 waves
    const int lane = i & 63;
    const int wv   = i >> 6;

    float f = focal_ws[i];
#pragma unroll
    for (int off = 32; off > 0; off >>= 1) f += __shfl_xor(f, off);

    __shared__ float red[4];
    if (lane == 0) red[wv] = f;
    __syncthreads();
    if (i == 0)
        out[0] = (red[0] + red[1] + red[2] + red[3]) * (1.0f / (float)Bb);
}

extern "C" void kernel_launch(void* const* d_in, const int* in_sizes, int n_in,
                              void* d_out, int out_size, void* d_ws, size_t ws_size,
                              hipStream_t stream) {
    const int*   y_true = (const int*)d_in[0];    // [B, L] int32
    const float* y_pred = (const float*)d_in[1];  // [B, T, V] float32
    float* focal_ws = (float*)d_ws;               // [B]

    fused_kernel<<<Bb, 1024, 0, stream>>>(y_true, y_pred, focal_ws);
    finalize_kernel<<<1, 256, 0, stream>>>(focal_ws, (float*)d_out);
}

// Round 4
// 200.783 us; speedup vs baseline: 1.6852x; 1.6810x over previous
//
#include <hip/hip_runtime.h>

// FocalCTCLoss on MI355X — round 9: 3-stage pipeline, NO lambdas anywhere.
// B=256, T=1024, V=128 (BLANK=127), L=64, S=129.
//
// Round-8 post-mortem: counters bit-identical to round 7 (VGPR 52, WRITE
// 16749 KB, dur 198.5 us) -> the staging arrays were never the scratch
// source. Revised theory: [&]-capturing phase lambdas take the address of
// the DP state / staging scalars; pipe_barrier()'s asm "memory" clobber
// (18x between capture and use) forces that state into an alloca ->
// scratch round-trip per DP step (~400 cy x 1024 steps ~= 190 us).
// Round 5 (45 us) differed exactly here: no asm clobber (__syncthreads).
//
// Fix: every phase body is a TEXTUAL macro expanded in kernel scope —
// preprocessor inlining cannot outline and captures nothing. No address
// of any live scalar is ever taken. Structure/math unchanged vs round 7/8:
// CH=64, 18 phases, lgkmcnt-only barriers, gather waves, rescale every 16
// steps at 2^-75.

#define EPSF 1e-7f

constexpr int Bb  = 256;
constexpr int Tt  = 1024;
constexpr int Vv  = 128;
constexpr int Ll  = 64;
constexpr int CH  = 64;          // timesteps per chunk
constexpr int NCH = Tt / CH;     // 16 chunks
constexpr int NPH = NCH + 2;     // 18 pipeline phases
constexpr int NLW = 13;          // loader waves (wv 3..15) -> 26 half-waves

// ---- DPP helpers -----------------------------------------------------------
template <int Ctrl, int RowMask, int BankMask, bool BoundCtrl>
__device__ __forceinline__ float dppf(float x) {
    return __int_as_float(__builtin_amdgcn_update_dpp(
        0, __float_as_int(x), Ctrl, RowMask, BankMask, BoundCtrl));
}

// Wave-64 sum, valid on lane 63 (inputs >= 0; 0-fill is identity).
__device__ __forceinline__ float wave_sum63(float x) {
    x += dppf<0x111, 0xf, 0xf, true>(x);
    x += dppf<0x112, 0xf, 0xf, true>(x);
    x += dppf<0x114, 0xf, 0xf, true>(x);
    x += dppf<0x118, 0xf, 0xf, true>(x);
    x += dppf<0x142, 0xa, 0xf, false>(x);  // row_bcast15 -> rows 1,3
    x += dppf<0x143, 0xc, 0xf, false>(x);  // row_bcast31 -> rows 2,3
    return x;
}

// Half-wave sums: lane 31 = sum(lanes 0..31), lane 63 = sum(lanes 32..63).
__device__ __forceinline__ float half_sum(float x) {
    x += dppf<0x111, 0xf, 0xf, true>(x);
    x += dppf<0x112, 0xf, 0xf, true>(x);
    x += dppf<0x114, 0xf, 0xf, true>(x);
    x += dppf<0x118, 0xf, 0xf, true>(x);
    x += dppf<0x142, 0xa, 0xf, false>(x);
    return x;
}

// Wave-64 max (non-negative inputs), valid on lane 63.
__device__ __forceinline__ float wave_max63(float x) {
    x = fmaxf(x, dppf<0x111, 0xf, 0xf, true>(x));
    x = fmaxf(x, dppf<0x112, 0xf, 0xf, true>(x));
    x = fmaxf(x, dppf<0x114, 0xf, 0xf, true>(x));
    x = fmaxf(x, dppf<0x118, 0xf, 0xf, true>(x));
    x = fmaxf(x, dppf<0x142, 0xa, 0xf, false>(x));
    x = fmaxf(x, dppf<0x143, 0xc, 0xf, false>(x));
    return x;
}

__device__ __forceinline__ float bcast63(float x) {
    return __int_as_float(__builtin_amdgcn_readlane(__float_as_int(x), 63));
}

// LDS-only barrier: order ds ops, do NOT drain vmcnt (keeps the loaders'
// next-chunk global loads in flight across the phase boundary).
#define PIPE_BARRIER()                                                       \
    do {                                                                     \
        asm volatile("s_waitcnt lgkmcnt(0)" ::: "memory");                   \
        __builtin_amdgcn_s_barrier();                                        \
        asm volatile("" ::: "memory");                                       \
    } while (0)

// ---- DP step (textual; updates a_even/a_odd/a128/eacc in enclosing scope) --
#define DO_STEP(QE, QB, CHK)                                                 \
    do {                                                                     \
        const float am1_ = dppf<0x138, 0xf, 0xf, true>(a_odd);               \
        const float ne_  = (a_even + am1_) * (QB);                           \
        const float no_  = fmaf(maskf, am1_, a_odd + a_even) * (QE);         \
        const float n1_  = (a128 + a_odd) * (QB);                            \
        a_even = ne_; a_odd = no_; a128 = n1_;                               \
        if (CHK) {                                                           \
            const float m_ = fmaxf(fmaxf(a_even, a_odd), a128);              \
            if (__all(m_ < 0x1p-75f)) {                                      \
                const float    wmax_  = bcast63(wave_max63(m_));             \
                const unsigned e_     = __float_as_uint(wmax_) >> 23;        \
                const float    scale_ = __uint_as_float((254u - e_) << 23);  \
                eacc += (int)e_ - 127;                                       \
                a_even *= scale_; a_odd *= scale_; a128 *= scale_;           \
            }                                                                \
        }                                                                    \
    } while (0)

// ---- loader phase P: issue chunk P+1 into N*, ds_write chunk P from C* -----
#define LOADER_PHASE(P, C0, C1, C2, N0, N1, N2)                              \
    do {                                                                     \
        if ((P) + 1 < NCH) {                                                 \
            const int gb_ = ((P) + 1) * CH * (Vv / 4);                       \
            N0 = yb4[gb_ + r0 * 32 + c32];                                   \
            N1 = yb4[gb_ + r1 * 32 + c32];                                   \
            if (r2ok) N2 = yb4[gb_ + r2 * 32 + c32];                         \
        }                                                                    \
        if ((P) < NCH) {                                                     \
            const int lb_ = ((P) & 1) * CH * (Vv / 4);                       \
            const int bb_ = ((P) & 3) * CH;                                  \
            tile4[lb_ + r0 * 32 + c32] = C0;                                 \
            tile4[lb_ + r1 * 32 + c32] = C1;                                 \
            const float s0_ = half_sum(C0.x + C0.y + C0.z + C0.w);           \
            const float s1_ = half_sum(C1.x + C1.y + C1.z + C1.w);           \
            if (c32 == 31) {                                                 \
                lblk[bb_ + r0] = C0.w + EPSF;                                \
                lblk[bb_ + r1] = C1.w + EPSF;                                \
                ll += __log2f(s0_ + (float)Vv * EPSF) +                      \
                      __log2f(s1_ + (float)Vv * EPSF);                       \
            }                                                                \
            if (r2ok) {                                                      \
                tile4[lb_ + r2 * 32 + c32] = C2;                             \
                const float s2_ = half_sum(C2.x + C2.y + C2.z + C2.w);       \
                if (c32 == 31) {                                             \
                    lblk[bb_ + r2] = C2.w + EPSF;                            \
                    ll += __log2f(s2_ + (float)Vv * EPSF);                   \
                }                                                            \
            }                                                                \
        } else if ((P) == NCH) {                                             \
            if (c32 == 31) part[hw] = ll;                                    \
        }                                                                    \
    } while (0)

// ---- gather phase P: compact tile[t][lab] of chunk P-1 into garr -----------
#define GATHER_PHASE(P)                                                      \
    do {                                                                     \
        const int c_ = (P) - 1;                                              \
        if (c_ >= 0 && c_ < NCH) {                                           \
            const int sb_ = (c_ & 1) * CH * Vv;                              \
            const int db_ = (c_ & 1) * CH * 64;                              \
            const int t0_ = (wv - 1) * 32;                                   \
            _Pragma("unroll 8")                                              \
            for (int t = t0_; t < t0_ + 32; ++t)                             \
                garr[db_ + t * 64 + lane] =                                  \
                    lrows[sb_ + t * 128 + lab] + EPSF;                       \
        }                                                                    \
    } while (0)

// ---- consumer sub-step with prefetch reload --------------------------------
#define CSTEP(J, GQ, BQ, CHK)                                                \
    do {                                                                     \
        const float qe_ = GQ, qb_ = BQ;                                      \
        const int   tn_ = t0 + (J) + 8;                                      \
        GQ = g_[tn_ * 64 + lane];                                            \
        BQ = bl_[tn_];                                                       \
        DO_STEP(qe_, qb_, CHK);                                              \
    } while (0)

// ---- consumer phase P: 64 DP steps of chunk P-2 from compact arrays --------
#define CONSUMER_PHASE(P)                                                    \
    do {                                                                     \
        const int c_ = (P) - 2;                                              \
        if (c_ >= 0) {                                                       \
            __builtin_amdgcn_s_setprio(1);                                   \
            const float* g_  = garr + (c_ & 1) * CH * 64;                    \
            const float* bl_ = lblk + (c_ & 3) * CH;                         \
            float gq0 = g_[0 * 64 + lane], gq1 = g_[1 * 64 + lane];          \
            float gq2 = g_[2 * 64 + lane], gq3 = g_[3 * 64 + lane];          \
            float gq4 = g_[4 * 64 + lane], gq5 = g_[5 * 64 + lane];          \
            float gq6 = g_[6 * 64 + lane], gq7 = g_[7 * 64 + lane];          \
            float bq0 = bl_[0], bq1 = bl_[1], bq2 = bl_[2], bq3 = bl_[3];    \
            float bq4 = bl_[4], bq5 = bl_[5], bq6 = bl_[6], bq7 = bl_[7];    \
            for (int t0 = 0; t0 < CH - 8; t0 += 8) {                         \
                const bool c8_ = (t0 & 8) != 0;                              \
                CSTEP(0, gq0, bq0, false);                                   \
                CSTEP(1, gq1, bq1, false);                                   \
                CSTEP(2, gq2, bq2, false);                                   \
                CSTEP(3, gq3, bq3, false);                                   \
                CSTEP(4, gq4, bq4, false);                                   \
                CSTEP(5, gq5, bq5, false);                                   \
                CSTEP(6, gq6, bq6, false);                                   \
                CSTEP(7, gq7, bq7, c8_);                                     \
            }                                                                \
            DO_STEP(gq0, bq0, false);                                        \
            DO_STEP(gq1, bq1, false);                                        \
            DO_STEP(gq2, bq2, false);                                        \
            DO_STEP(gq3, bq3, false);                                        \
            DO_STEP(gq4, bq4, false);                                        \
            DO_STEP(gq5, bq5, false);                                        \
            DO_STEP(gq6, bq6, false);                                        \
            DO_STEP(gq7, bq7, true);                                         \
            __builtin_amdgcn_s_setprio(0);                                   \
        }                                                                    \
    } while (0)

// ---- fused 3-stage pipeline: one block per batch element -------------------
__launch_bounds__(1024, 1)
__global__ void fused_kernel(const int* __restrict__ y_true,
                             const float* __restrict__ y_pred,
                             float* __restrict__ focal_ws) {
    const int b    = blockIdx.x;
    const int lane = threadIdx.x & 63;
    const int wv   = threadIdx.x >> 6;  // 0..15

    const float4* yb4 = (const float4*)(y_pred + (size_t)b * Tt * Vv);

    __shared__ float4 tile4[2 * CH * (Vv / 4)];  // 64 KB: raw chunk rows
    __shared__ float  garr[2 * CH * 64];         // 32 KB: gathered qe per t
    __shared__ float  lblk[4 * CH];              //  1 KB: blank+eps per t
    __shared__ float  part[2 * NLW];             // denom log partials
    const float* lrows = (const float*)tile4;

    // ---- DP state (wave 0; meaningful on lane 63) --------------------------
    float a_even = 0.0f, a_odd = 0.0f, a128 = 0.0f, maskf = 0.0f;
    int   eacc = 0, lab = 0;

    if (wv <= 2) {
        lab = y_true[b * Ll + lane];           // label of odd state 2*lane+1
        if (wv == 0) {
            const int labp = __shfl_up(lab, 1);
            maskf  = (lane == 0 || lab != labp) ? 1.0f : 0.0f;
            a_even = (lane == 0) ? 1.0f : 0.0f;  // pre-t0 init
        }
    }

    // ---- loader identity ---------------------------------------------------
    const int  half = lane >> 5;
    const int  hw   = 2 * (wv - 3) + half;  // half-wave id 0..25 (wv>=3)
    const int  c32  = lane & 31;
    const int  r0   = hw;                   // 0..25  (< CH always)
    const int  r1   = hw + 2 * NLW;         // 26..51 (< CH always)
    const int  r2   = hw + 4 * NLW;         // 52..77 (guarded)
    const bool r2ok = r2 < CH;              // wave-uniform (both halves agree)
    float ll = 0.0f;                        // lanes 31/63: sum log2 row-sums

    // Named staging registers — never address-taken, no lambdas see them.
    float4 va0, va1, va2, vb0, vb1, vb2;

    // prologue: chunk 0 into va*
    if (wv >= 3) {
        va0 = yb4[r0 * 32 + c32];
        va1 = yb4[r1 * 32 + c32];
        if (r2ok) va2 = yb4[r2 * 32 + c32];
    }

    // ---- 18 phases, 2 per iteration so the staging reg sets alternate ------
    for (int p = 0; p < NPH; p += 2) {
        if (wv >= 3)      LOADER_PHASE(p, va0, va1, va2, vb0, vb1, vb2);
        else if (wv >= 1) GATHER_PHASE(p);
        else              CONSUMER_PHASE(p);
        PIPE_BARRIER();
        if (wv >= 3)      LOADER_PHASE(p + 1, vb0, vb1, vb2, va0, va1, va2);
        else if (wv >= 1) GATHER_PHASE(p + 1);
        else              CONSUMER_PHASE(p + 1);
        PIPE_BARRIER();
    }

    if (wv == 0) {
        float vs = (lane < 2 * NLW) ? part[lane] : 0.0f;
        vs = wave_sum63(vs);
        if (lane == 63) {
            const float acc_ld  = vs;  // sum_t log2(S_t + V*eps)
            const float tot     = fmaxf(a128 + a_odd, 1e-37f);
            const float log2lik = __log2f(tot) + (float)eacc - acc_ld;
            const float ln_lik  = 0.69314718055994530942f * log2lik;
            const float loss    = -ln_lik;
            const float pp      = __expf(ln_lik);
            const float om      = 1.0f - pp;
            focal_ws[b] = 0.25f * om * om * loss;
        }
    }
}

// ---- focal mean -------------------------------------------------------------
__global__ void finalize_kernel(const float* __restrict__ focal_ws,
                                float* __restrict__ out) {
    const int i    = threadIdx.x;  // 256 threads = 4 waves
    const int lane = i & 63;
    const int wv   = i >> 6;

    float f = focal_ws[i];
#pragma unroll
    for (int off = 32; off > 0; off >>= 1) f += __shfl_xor(f, off);

    __shared__ float red[4];
    if (lane == 0) red[wv] = f;
    __syncthreads();
    if (i == 0)
        out[0] = (red[0] + red[1] + red[2] + red[3]) * (1.0f / (float)Bb);
}

extern "C" void kernel_launch(void* const* d_in, const int* in_sizes, int n_in,
                              void* d_out, int out_size, void* d_ws, size_t ws_size,
                              hipStream_t stream) {
    const int*   y_true = (const int*)d_in[0];    // [B, L] int32
    const float* y_pred = (const float*)d_in[1];  // [B, T, V] float32
    float* focal_ws = (float*)d_ws;               // [B]

    fused_kernel<<<Bb, 1024, 0, stream>>>(y_true, y_pred, focal_ws);
    finalize_kernel<<<1, 256, 0, stream>>>(focal_ws, (float*)d_out);
}